// Round 1
// baseline (2154.872 us; speedup 1.0000x reference)
//
#include <hip/hip_runtime.h>
#include <math.h>

#define NN 30000
#define MM 16
#define F 128
#define NMROWS (NN*MM)
constexpr float BN_EPS = 1e-5f;

// ---- workspace float offsets ----
#define WS_NODE   0u
#define WS_S      3840000u
#define WS_T      7680000u
#define WS_SUM    11520000u
#define WS_LOGIT  15360000u
#define WS_RED    15840000u
#define WS_SCAL   15840512u
#define WS_STATS  15841024u
// within stats region:
#define ST_BN1SUM 0u
#define ST_BN1SQ  384u
#define ST_BN2SUM 768u
#define ST_BN2SQ  1152u
#define ST_SC1    1536u
#define ST_SH1    1664u
#define ST_SC2    1792u
#define ST_SH2    1920u
#define ST_W1E    2048u
#define ST_W1D    2688u
#define ST_B1EFF  2816u
#define ST_END    2944u

__device__ __forceinline__ float read_tp(const int* tp) {
  // hedge: tp_type may arrive as int32 or as float bits
  int ti = tp[0];
  return (ti >= -1000 && ti <= 1000) ? (float)ti : __int_as_float(ti);
}

// node = node_fea @ emb_W + emb_b
__global__ void k_embed(const float* __restrict__ nf, const float* __restrict__ W,
                        const float* __restrict__ b, float* __restrict__ node) {
  int i = blockIdx.x*256 + threadIdx.x;
  if (i >= NN*F) return;
  int n = i >> 7, c = i & 127;
  float acc = b[c];
  const float* r = nf + n*19;
  #pragma unroll
  for (int k = 0; k < 19; ++k) acc = fmaf(r[k], W[k*F + c], acc);
  node[i] = acc;
}

// S[n][c] = sum_k node[n][k]*Wl[k][c] + bl[c] ; T[n][c] = sum_k node[n][k]*Wl[128+k][c]
// Wl row width 256, we use c<128. 8 nodes/block, 256 threads.
__global__ void k_st(const float* __restrict__ node, const float* __restrict__ Wl,
                     const float* __restrict__ bl, float* __restrict__ S, float* __restrict__ T) {
  __shared__ float nd[8][F];
  int n0 = blockIdx.x*8;
  for (int i = threadIdx.x; i < 8*F; i += 256) nd[i>>7][i&127] = node[n0*F + i];
  __syncthreads();
  int r = threadIdx.x >> 5;
  int cg = (threadIdx.x & 31)*4;
  float4 sa = {0,0,0,0}, ta = {0,0,0,0};
  const float* ws0 = Wl + cg;
  const float* wn0 = Wl + 128*256 + cg;
  for (int k = 0; k < F; ++k) {
    float a = nd[r][k];
    float4 w1 = *(const float4*)(ws0 + (size_t)k*256);
    float4 w2 = *(const float4*)(wn0 + (size_t)k*256);
    sa.x = fmaf(a,w1.x,sa.x); sa.y = fmaf(a,w1.y,sa.y); sa.z = fmaf(a,w1.z,sa.z); sa.w = fmaf(a,w1.w,sa.w);
    ta.x = fmaf(a,w2.x,ta.x); ta.y = fmaf(a,w2.y,ta.y); ta.z = fmaf(a,w2.z,ta.z); ta.w = fmaf(a,w2.w,ta.w);
  }
  int n = n0 + r;
  float4 bb = *(const float4*)(bl + cg);
  sa.x += bb.x; sa.y += bb.y; sa.z += bb.z; sa.w += bb.w;
  *(float4*)&S[(size_t)n*F + cg] = sa;
  *(float4*)&T[(size_t)n*F + cg] = ta;
}

// U[n][c] = sum_k node[n][k]*W1[k][c] + b1eff[c]   (W1 row width 128)
__global__ void k_u(const float* __restrict__ node, const float* __restrict__ W1,
                    const float* __restrict__ b1eff, float* __restrict__ U) {
  __shared__ float nd[8][F];
  int n0 = blockIdx.x*8;
  for (int i = threadIdx.x; i < 8*F; i += 256) nd[i>>7][i&127] = node[n0*F + i];
  __syncthreads();
  int r = threadIdx.x >> 5;
  int cg = (threadIdx.x & 31)*4;
  float4 acc = {0,0,0,0};
  const float* wp = W1 + cg;
  for (int k = 0; k < F; ++k) {
    float a = nd[r][k];
    float4 w = *(const float4*)(wp + (size_t)k*128);
    acc.x = fmaf(a,w.x,acc.x); acc.y = fmaf(a,w.y,acc.y);
    acc.z = fmaf(a,w.z,acc.z); acc.w = fmaf(a,w.w,acc.w);
  }
  float4 bb = *(const float4*)(b1eff + cg);
  acc.x += bb.x; acc.y += bb.y; acc.z += bb.z; acc.w += bb.w;
  *(float4*)&U[(size_t)(n0+r)*F + cg] = acc;
}

// pass 1: bn1 stats over ALL 480000 rows (channels 0..127). 16 nodes/block.
__global__ void k_conv_stats(const float* __restrict__ S, const float* __restrict__ T,
                             const float* __restrict__ Wl, const float* __restrict__ edge,
                             const int* __restrict__ idx,
                             float* __restrict__ bsum, float* __restrict__ bsq) {
  __shared__ float eL[16*16*5];
  __shared__ int gL[256];
  __shared__ float rA[256], rB[256];
  int n0 = blockIdx.x*16;
  for (int i = threadIdx.x; i < 1280; i += 256) eL[i] = edge[(size_t)n0*80 + i];
  {
    int v = idx[n0*MM + threadIdx.x];
    gL[threadIdx.x] = v < 0 ? v + NN : v;   // torch-style negative wrap
  }
  __syncthreads();
  int c = threadIdx.x & 127, h = threadIdx.x >> 7;
  float we[5];
  #pragma unroll
  for (int j = 0; j < 5; ++j) we[j] = Wl[(size_t)(256+j)*256 + c];
  float s1 = 0.f, s2 = 0.f;
  for (int nl = h*8; nl < h*8 + 8; ++nl) {
    float sv = S[(size_t)(n0+nl)*F + c];
    for (int m = 0; m < MM; ++m) {
      int row = nl*MM + m;
      float g = sv + T[(size_t)gL[row]*F + c];
      const float* e = &eL[row*5];
      #pragma unroll
      for (int j = 0; j < 5; ++j) g = fmaf(e[j], we[j], g);
      s1 += g; s2 = fmaf(g, g, s2);
    }
  }
  rA[threadIdx.x] = s1; rB[threadIdx.x] = s2;
  __syncthreads();
  if (h == 0) {
    atomicAdd(&bsum[c], s1 + rA[128 + c]);
    atomicAdd(&bsq[c],  s2 + rB[128 + c]);
  }
}

__global__ void k_bn_fin(const float* __restrict__ sum, const float* __restrict__ sq,
                         const float* __restrict__ gamma, const float* __restrict__ beta,
                         float* __restrict__ sc, float* __restrict__ sh, float inv_n) {
  int c = threadIdx.x;
  float mu = sum[c]*inv_n;
  float var = sq[c]*inv_n - mu*mu;
  float s = gamma[c] / sqrtf(var + BN_EPS);
  sc[c] = s;
  sh[c] = beta[c] - mu*s;
}

// pass 2: summed[n][c] = sum_m mask*sigmoid(bn(g))^2 ; bn2 stats over 30000 rows. 4 nodes/block, 512 thr.
__global__ void k_conv_pass2(const float* __restrict__ S, const float* __restrict__ T,
                             const float* __restrict__ Wl, const float* __restrict__ edge,
                             const int* __restrict__ idx,
                             const float* __restrict__ sc1, const float* __restrict__ sh1,
                             float* __restrict__ summed, float* __restrict__ bsum, float* __restrict__ bsq) {
  __shared__ float eL[4*16*5];
  __shared__ int gL[64];
  __shared__ float mk[64];
  __shared__ float rA[512], rB[512];
  int n0 = blockIdx.x*4;
  for (int i = threadIdx.x; i < 320; i += 512) eL[i] = edge[(size_t)n0*80 + i];
  if (threadIdx.x < 64) {
    int v = idx[n0*MM + threadIdx.x];
    mk[threadIdx.x] = v >= 0 ? 1.f : 0.f;
    gL[threadIdx.x] = v < 0 ? v + NN : v;
  }
  __syncthreads();
  int c = threadIdx.x & 127, q = threadIdx.x >> 7;
  float we[5];
  #pragma unroll
  for (int j = 0; j < 5; ++j) we[j] = Wl[(size_t)(256+j)*256 + c];
  float s = sc1[c], b = sh1[c];
  float sv = S[(size_t)(n0+q)*F + c];
  float acc = 0.f;
  for (int m = 0; m < MM; ++m) {
    int row = q*MM + m;
    float g = sv + T[(size_t)gL[row]*F + c];
    const float* e = &eL[row*5];
    #pragma unroll
    for (int j = 0; j < 5; ++j) g = fmaf(e[j], we[j], g);
    float x = fmaf(g, s, b);
    float sig = 1.f/(1.f + expf(-x));
    acc = fmaf(mk[row]*sig, sig, acc);   // filt*core = sigmoid^2 * mask
  }
  summed[(size_t)(n0+q)*F + c] = acc;
  rA[threadIdx.x] = acc; rB[threadIdx.x] = acc*acc;
  __syncthreads();
  if (q == 0) {
    atomicAdd(&bsum[c], rA[c]+rA[128+c]+rA[256+c]+rA[384+c]);
    atomicAdd(&bsq[c],  rB[c]+rB[128+c]+rB[256+c]+rB[384+c]);
  }
}

// node = softplus(node + bn2(summed))
__global__ void k_update(float* __restrict__ node, const float* __restrict__ summed,
                         const float* __restrict__ sc, const float* __restrict__ sh) {
  int i = blockIdx.x*256 + threadIdx.x;
  if (i >= NN*F) return;
  int c = i & 127;
  float x = node[i] + fmaf(summed[i], sc[c], sh[c]);
  node[i] = fmaxf(x, 0.f) + log1pf(expf(-fabsf(x)));
}

// fold tiled-edge / repeated-distance / constant-tp columns of pi_W1
__global__ void k_pi_const(const float* __restrict__ W1, const float* __restrict__ b1,
                           const int* __restrict__ tp,
                           float* __restrict__ w1e, float* __restrict__ w1d, float* __restrict__ b1eff) {
  int c = threadIdx.x;
  float t = read_tp(tp);
  #pragma unroll
  for (int j = 0; j < 5; ++j) w1e[j*128 + c] = W1[(128+j)*128 + c] + W1[(133+j)*128 + c];
  float d = 0.f;
  #pragma unroll
  for (int r = 138; r < 143; ++r) d += W1[r*128 + c];
  w1d[c] = d;
  float tt = 0.f;
  #pragma unroll
  for (int r = 143; r < 148; ++r) tt += W1[r*128 + c];
  b1eff[c] = b1[c] + t*tt;
}

// fused pi MLP: 32 rows (2 nodes) per 256-thread block; h1/h2/h3 tiles in LDS
__global__ __launch_bounds__(256) void k_pi(
    const float* __restrict__ U, const float* __restrict__ W2, const float* __restrict__ b2,
    const float* __restrict__ W3, const float* __restrict__ b3,
    const float* __restrict__ W4, const float* __restrict__ b4,
    const float* __restrict__ edge, const int* __restrict__ idx, const float* __restrict__ dist,
    const int* __restrict__ tp,
    const float* __restrict__ w1e, const float* __restrict__ w1d,
    float* __restrict__ lgt) {
  __shared__ float h1[32][F];        // reused as h3
  __shared__ float h2[32][256];
  __shared__ float eeL[32][5];
  __shared__ float ddL[32];
  __shared__ int gxL[32], ivL[32];
  int rb = blockIdx.x*32;
  for (int i = threadIdx.x; i < 160; i += 256) eeL[i/5][i%5] = edge[(size_t)rb*5 + i];
  if (threadIdx.x < 32) {
    int v = idx[rb + threadIdx.x];
    ivL[threadIdx.x] = v;
    gxL[threadIdx.x] = v < 0 ? v + NN : v;
    ddL[threadIdx.x] = dist[rb + threadIdx.x];
  }
  __syncthreads();
  // stage A: h1 = relu(U[gather] + e@W1e + d*w1d)
  {
    int c = threadIdx.x & 127, rh = threadIdx.x >> 7;
    float wd = w1d[c];
    float wE[5];
    #pragma unroll
    for (int j = 0; j < 5; ++j) wE[j] = w1e[j*128 + c];
    for (int r = rh*16; r < rh*16 + 16; ++r) {
      float v = U[(size_t)gxL[r]*F + c];
      v = fmaf(ddL[r], wd, v);
      #pragma unroll
      for (int j = 0; j < 5; ++j) v = fmaf(eeL[r][j], wE[j], v);
      h1[r][c] = fmaxf(v, 0.f);
    }
  }
  __syncthreads();
  // stage B: h2 = relu(h1 @ W2 + b2)   (32x128 @ 128x256)
  {
    int tc4 = (threadIdx.x & 63)*4, tr = threadIdx.x >> 6;
    float4 acc[8];
    #pragma unroll
    for (int i = 0; i < 8; ++i) acc[i] = make_float4(0.f,0.f,0.f,0.f);
    const float* wp = W2 + tc4;
    for (int k = 0; k < 128; ++k) {
      float4 w = *(const float4*)(wp + (size_t)k*256);
      #pragma unroll
      for (int i = 0; i < 8; ++i) {
        float a = h1[tr*8 + i][k];
        acc[i].x = fmaf(a,w.x,acc[i].x); acc[i].y = fmaf(a,w.y,acc[i].y);
        acc[i].z = fmaf(a,w.z,acc[i].z); acc[i].w = fmaf(a,w.w,acc[i].w);
      }
    }
    float4 bb = *(const float4*)(b2 + tc4);
    #pragma unroll
    for (int i = 0; i < 8; ++i) {
      float4 v;
      v.x = fmaxf(acc[i].x + bb.x, 0.f); v.y = fmaxf(acc[i].y + bb.y, 0.f);
      v.z = fmaxf(acc[i].z + bb.z, 0.f); v.w = fmaxf(acc[i].w + bb.w, 0.f);
      *(float4*)&h2[tr*8 + i][tc4] = v;
    }
  }
  __syncthreads();
  // stage C: h3 = relu(h2 @ W3 + b3)  (32x256 @ 256x128) -> into h1 buffer
  {
    int tc4 = (threadIdx.x & 31)*4, tr = threadIdx.x >> 5;
    float4 acc[4];
    #pragma unroll
    for (int i = 0; i < 4; ++i) acc[i] = make_float4(0.f,0.f,0.f,0.f);
    const float* wp = W3 + tc4;
    for (int k = 0; k < 256; ++k) {
      float4 w = *(const float4*)(wp + (size_t)k*128);
      #pragma unroll
      for (int i = 0; i < 4; ++i) {
        float a = h2[tr*4 + i][k];
        acc[i].x = fmaf(a,w.x,acc[i].x); acc[i].y = fmaf(a,w.y,acc[i].y);
        acc[i].z = fmaf(a,w.z,acc[i].z); acc[i].w = fmaf(a,w.w,acc[i].w);
      }
    }
    float4 bb = *(const float4*)(b3 + tc4);
    #pragma unroll
    for (int i = 0; i < 4; ++i) {
      float4 v;
      v.x = fmaxf(acc[i].x + bb.x, 0.f); v.y = fmaxf(acc[i].y + bb.y, 0.f);
      v.z = fmaxf(acc[i].z + bb.z, 0.f); v.w = fmaxf(acc[i].w + bb.w, 0.f);
      *(float4*)&h1[tr*4 + i][tc4] = v;   // h1 fully consumed in stage B (barrier above)
    }
  }
  __syncthreads();
  // stage D: logit = h3 @ W4 + b4, apply 1e8 mask, store
  {
    int r = threadIdx.x >> 3, s = threadIdx.x & 7;
    const float* h3r = h1[r];
    float p = 0.f;
    #pragma unroll
    for (int kk = 0; kk < 16; ++kk) {
      int k = s*16 + kk;
      p = fmaf(h3r[k], W4[k], p);
    }
    p += __shfl_xor(p, 1, 8);
    p += __shfl_xor(p, 2, 8);
    p += __shfl_xor(p, 4, 8);
    if (s == 0) {
      float tpf = read_tp(tp);
      float lg = p + b4[0];
      float am = (ivL[r] >= 0 && eeL[r][4] <= tpf) ? 0.f : 1.f;
      lgt[rb + r] = lg - 1e8f*am;
    }
  }
}

__global__ void k_rmax(const float* __restrict__ lg, float* __restrict__ red) {
  float m = -1e30f;
  for (int i = blockIdx.x*256 + threadIdx.x; i < NMROWS; i += 512*256)
    m = fmaxf(m, lg[i]);
  __shared__ float r[256];
  r[threadIdx.x] = m;
  __syncthreads();
  for (int s = 128; s > 0; s >>= 1) {
    if (threadIdx.x < s) r[threadIdx.x] = fmaxf(r[threadIdx.x], r[threadIdx.x + s]);
    __syncthreads();
  }
  if (threadIdx.x == 0) red[blockIdx.x] = r[0];
}

__global__ void k_fmax(const float* __restrict__ red, float* __restrict__ scal) {
  __shared__ float r[512];
  r[threadIdx.x] = red[threadIdx.x];
  __syncthreads();
  for (int s = 256; s > 0; s >>= 1) {
    if (threadIdx.x < s) r[threadIdx.x] = fmaxf(r[threadIdx.x], r[threadIdx.x + s]);
    __syncthreads();
  }
  if (threadIdx.x == 0) scal[0] = r[0];
}

__global__ void k_rsum(const float* __restrict__ lg, const float* __restrict__ scal,
                       float* __restrict__ red) {
  float gm = scal[0];
  float s = 0.f;
  for (int i = blockIdx.x*256 + threadIdx.x; i < NMROWS; i += 512*256)
    s += expf(lg[i] - gm);
  __shared__ float r[256];
  r[threadIdx.x] = s;
  __syncthreads();
  for (int t = 128; t > 0; t >>= 1) {
    if (threadIdx.x < t) r[threadIdx.x] += r[threadIdx.x + t];
    __syncthreads();
  }
  if (threadIdx.x == 0) red[blockIdx.x] = r[0];
}

__global__ void k_fsum(const float* __restrict__ red, float* __restrict__ scal) {
  __shared__ float r[512];
  r[threadIdx.x] = red[threadIdx.x];
  __syncthreads();
  for (int s = 256; s > 0; s >>= 1) {
    if (threadIdx.x < s) r[threadIdx.x] += r[threadIdx.x + s];
    __syncthreads();
  }
  if (threadIdx.x == 0) { scal[1] = r[0]; scal[2] = 1.f/r[0]; }
}

__global__ void k_out(const float* __restrict__ lg, const float* __restrict__ scal,
                      float* __restrict__ out) {
  int i = blockIdx.x*256 + threadIdx.x;
  if (i >= NMROWS) return;
  out[i] = expf(lg[i] - scal[0]) * scal[2];
}

extern "C" void kernel_launch(void* const* d_in, const int* in_sizes, int n_in,
                              void* d_out, int out_size, void* d_ws, size_t ws_size,
                              hipStream_t stream) {
  (void)in_sizes; (void)n_in; (void)out_size;
  const float* node_fea = (const float*)d_in[0];
  const float* edge_fea = (const float*)d_in[1];
  const int*   eidx     = (const int*)d_in[2];
  const float* dist     = (const float*)d_in[3];
  const int*   tp       = (const int*)d_in[4];
  const float* emb_W    = (const float*)d_in[5];
  const float* emb_b    = (const float*)d_in[6];
  const float* cW       = (const float*)d_in[7];
  const float* cb       = (const float*)d_in[8];
  const float* bn1g     = (const float*)d_in[9];
  const float* bn1b     = (const float*)d_in[10];
  const float* bn2g     = (const float*)d_in[11];
  const float* bn2b     = (const float*)d_in[12];
  const float* pW1      = (const float*)d_in[13];
  const float* pb1      = (const float*)d_in[14];
  const float* pW2      = (const float*)d_in[15];
  const float* pb2      = (const float*)d_in[16];
  const float* pW3      = (const float*)d_in[17];
  const float* pb3      = (const float*)d_in[18];
  const float* pW4      = (const float*)d_in[19];
  const float* pb4      = (const float*)d_in[20];
  float* out = (float*)d_out;
  float* ws  = (float*)d_ws;

  if (ws_size < (size_t)(WS_STATS + ST_END)*sizeof(float)) return;  // need ~63.4 MB

  float* stats = ws + WS_STATS;
  hipMemsetAsync(stats, 0, 1536*sizeof(float), stream);  // zero bn sum/sumsq accumulators

  k_embed<<<15000, 256, 0, stream>>>(node_fea, emb_W, emb_b, ws + WS_NODE);

  for (int l = 0; l < 3; ++l) {
    const float* Wl = cW + (size_t)l*261*256;
    k_st<<<3750, 256, 0, stream>>>(ws + WS_NODE, Wl, cb + l*256, ws + WS_S, ws + WS_T);
    k_conv_stats<<<1875, 256, 0, stream>>>(ws + WS_S, ws + WS_T, Wl, edge_fea, eidx,
                                           stats + ST_BN1SUM + l*128, stats + ST_BN1SQ + l*128);
    k_bn_fin<<<1, 128, 0, stream>>>(stats + ST_BN1SUM + l*128, stats + ST_BN1SQ + l*128,
                                    bn1g + l*256, bn1b + l*256,
                                    stats + ST_SC1, stats + ST_SH1, 1.f/NMROWS);
    k_conv_pass2<<<7500, 512, 0, stream>>>(ws + WS_S, ws + WS_T, Wl, edge_fea, eidx,
                                           stats + ST_SC1, stats + ST_SH1,
                                           ws + WS_SUM, stats + ST_BN2SUM + l*128, stats + ST_BN2SQ + l*128);
    k_bn_fin<<<1, 128, 0, stream>>>(stats + ST_BN2SUM + l*128, stats + ST_BN2SQ + l*128,
                                    bn2g + l*128, bn2b + l*128,
                                    stats + ST_SC2, stats + ST_SH2, 1.f/NN);
    k_update<<<15000, 256, 0, stream>>>(ws + WS_NODE, ws + WS_SUM, stats + ST_SC2, stats + ST_SH2);
  }

  k_pi_const<<<1, 128, 0, stream>>>(pW1, pb1, tp, stats + ST_W1E, stats + ST_W1D, stats + ST_B1EFF);
  k_u<<<3750, 256, 0, stream>>>(ws + WS_NODE, pW1, stats + ST_B1EFF, ws + WS_S);
  k_pi<<<15000, 256, 0, stream>>>(ws + WS_S, pW2, pb2, pW3, pb3, pW4, pb4,
                                  edge_fea, eidx, dist, tp,
                                  stats + ST_W1E, stats + ST_W1D, ws + WS_LOGIT);

  k_rmax<<<512, 256, 0, stream>>>(ws + WS_LOGIT, ws + WS_RED);
  k_fmax<<<1, 512, 0, stream>>>(ws + WS_RED, ws + WS_SCAL);
  k_rsum<<<512, 256, 0, stream>>>(ws + WS_LOGIT, ws + WS_SCAL, ws + WS_RED);
  k_fsum<<<1, 512, 0, stream>>>(ws + WS_RED, ws + WS_SCAL);
  k_out<<<1875, 256, 0, stream>>>(ws + WS_LOGIT, ws + WS_SCAL, out);
}

// Round 2
// 1767.276 us; speedup vs baseline: 1.2193x; 1.2193x over previous
//
#include <hip/hip_runtime.h>
#include <hip/hip_bf16.h>
#include <math.h>

#define NN 30000
#define MM 16
#define F 128
#define NMROWS (NN*MM)
constexpr float BN_EPS = 1e-5f;

using bf16x8 = __attribute__((ext_vector_type(8))) short;
using f32x4v = __attribute__((ext_vector_type(4))) float;

// ---- workspace float offsets ----
#define WS_NODE   0u
#define WS_S      3840000u
#define WS_T      7680000u
#define WS_SUM    11520000u
#define WS_LOGIT  15360000u
#define WS_RED    15840000u
#define WS_SCAL   15840512u
#define WS_STATS  15841024u
// within stats region:
#define ST_BN1SUM 0u
#define ST_BN1SQ  384u
#define ST_BN2SUM 768u
#define ST_BN2SQ  1152u
#define ST_SC1    1536u
#define ST_SH1    1664u
#define ST_SC2    1792u
#define ST_SH2    1920u
#define ST_W1E    2048u
#define ST_W1D    2688u
#define ST_B1EFF  2816u
#define ST_END    2944u

__device__ __forceinline__ float read_tp(const int* tp) {
  int ti = tp[0];
  return (ti >= -1000 && ti <= 1000) ? (float)ti : __int_as_float(ti);
}

// exact 3-chunk bf16 split (truncation; x = c0 + c1 + c2 + O(2^-24 x))
__device__ __forceinline__ void split3(float x, short& a, short& b, short& c) {
  unsigned u0 = __float_as_uint(x);
  a = (short)(u0 >> 16);
  float r1 = x - __uint_as_float(u0 & 0xFFFF0000u);
  unsigned u1 = __float_as_uint(r1);
  b = (short)(u1 >> 16);
  float r2 = r1 - __uint_as_float(u1 & 0xFFFF0000u);
  c = (short)(__float_as_uint(r2) >> 16);
}

// node = node_fea @ emb_W + emb_b
__global__ void k_embed(const float* __restrict__ nf, const float* __restrict__ W,
                        const float* __restrict__ b, float* __restrict__ node) {
  int i = blockIdx.x*256 + threadIdx.x;
  if (i >= NN*F) return;
  int n = i >> 7, c = i & 127;
  float acc = b[c];
  const float* r = nf + n*19;
  #pragma unroll
  for (int k = 0; k < 19; ++k) acc = fmaf(r[k], W[k*F + c], acc);
  node[i] = acc;
}

// S[n][c], T[n][c] from conv weight halves
__global__ void k_st(const float* __restrict__ node, const float* __restrict__ Wl,
                     const float* __restrict__ bl, float* __restrict__ S, float* __restrict__ T) {
  __shared__ float nd[8][F];
  int n0 = blockIdx.x*8;
  for (int i = threadIdx.x; i < 8*F; i += 256) nd[i>>7][i&127] = node[n0*F + i];
  __syncthreads();
  int r = threadIdx.x >> 5;
  int cg = (threadIdx.x & 31)*4;
  float4 sa = {0,0,0,0}, ta = {0,0,0,0};
  const float* ws0 = Wl + cg;
  const float* wn0 = Wl + 128*256 + cg;
  for (int k = 0; k < F; ++k) {
    float a = nd[r][k];
    float4 w1 = *(const float4*)(ws0 + (size_t)k*256);
    float4 w2 = *(const float4*)(wn0 + (size_t)k*256);
    sa.x = fmaf(a,w1.x,sa.x); sa.y = fmaf(a,w1.y,sa.y); sa.z = fmaf(a,w1.z,sa.z); sa.w = fmaf(a,w1.w,sa.w);
    ta.x = fmaf(a,w2.x,ta.x); ta.y = fmaf(a,w2.y,ta.y); ta.z = fmaf(a,w2.z,ta.z); ta.w = fmaf(a,w2.w,ta.w);
  }
  int n = n0 + r;
  float4 bb = *(const float4*)(bl + cg);
  sa.x += bb.x; sa.y += bb.y; sa.z += bb.z; sa.w += bb.w;
  *(float4*)&S[(size_t)n*F + cg] = sa;
  *(float4*)&T[(size_t)n*F + cg] = ta;
}

// U[n][c] = node @ pi_W1 + b1eff
__global__ void k_u(const float* __restrict__ node, const float* __restrict__ W1,
                    const float* __restrict__ b1eff, float* __restrict__ U) {
  __shared__ float nd[8][F];
  int n0 = blockIdx.x*8;
  for (int i = threadIdx.x; i < 8*F; i += 256) nd[i>>7][i&127] = node[n0*F + i];
  __syncthreads();
  int r = threadIdx.x >> 5;
  int cg = (threadIdx.x & 31)*4;
  float4 acc = {0,0,0,0};
  const float* wp = W1 + cg;
  for (int k = 0; k < F; ++k) {
    float a = nd[r][k];
    float4 w = *(const float4*)(wp + (size_t)k*128);
    acc.x = fmaf(a,w.x,acc.x); acc.y = fmaf(a,w.y,acc.y);
    acc.z = fmaf(a,w.z,acc.z); acc.w = fmaf(a,w.w,acc.w);
  }
  float4 bb = *(const float4*)(b1eff + cg);
  acc.x += bb.x; acc.y += bb.y; acc.z += bb.z; acc.w += bb.w;
  *(float4*)&U[(size_t)(n0+r)*F + cg] = acc;
}

// pass 1: bn1 stats over all 480000 rows (channels 0..127)
__global__ void k_conv_stats(const float* __restrict__ S, const float* __restrict__ T,
                             const float* __restrict__ Wl, const float* __restrict__ edge,
                             const int* __restrict__ idx,
                             float* __restrict__ bsum, float* __restrict__ bsq) {
  __shared__ float eL[16*16*5];
  __shared__ int gL[256];
  __shared__ float rA[256], rB[256];
  int n0 = blockIdx.x*16;
  for (int i = threadIdx.x; i < 1280; i += 256) eL[i] = edge[(size_t)n0*80 + i];
  {
    int v = idx[n0*MM + threadIdx.x];
    gL[threadIdx.x] = v < 0 ? v + NN : v;
  }
  __syncthreads();
  int c = threadIdx.x & 127, h = threadIdx.x >> 7;
  float we[5];
  #pragma unroll
  for (int j = 0; j < 5; ++j) we[j] = Wl[(size_t)(256+j)*256 + c];
  float s1 = 0.f, s2 = 0.f;
  for (int nl = h*8; nl < h*8 + 8; ++nl) {
    float sv = S[(size_t)(n0+nl)*F + c];
    for (int m = 0; m < MM; ++m) {
      int row = nl*MM + m;
      float g = sv + T[(size_t)gL[row]*F + c];
      const float* e = &eL[row*5];
      #pragma unroll
      for (int j = 0; j < 5; ++j) g = fmaf(e[j], we[j], g);
      s1 += g; s2 = fmaf(g, g, s2);
    }
  }
  rA[threadIdx.x] = s1; rB[threadIdx.x] = s2;
  __syncthreads();
  if (h == 0) {
    atomicAdd(&bsum[c], s1 + rA[128 + c]);
    atomicAdd(&bsq[c],  s2 + rB[128 + c]);
  }
}

__global__ void k_bn_fin(const float* __restrict__ sum, const float* __restrict__ sq,
                         const float* __restrict__ gamma, const float* __restrict__ beta,
                         float* __restrict__ sc, float* __restrict__ sh, float inv_n) {
  int c = threadIdx.x;
  float mu = sum[c]*inv_n;
  float var = sq[c]*inv_n - mu*mu;
  float s = gamma[c] / sqrtf(var + BN_EPS);
  sc[c] = s;
  sh[c] = beta[c] - mu*s;
}

// pass 2: summed + bn2 stats
__global__ void k_conv_pass2(const float* __restrict__ S, const float* __restrict__ T,
                             const float* __restrict__ Wl, const float* __restrict__ edge,
                             const int* __restrict__ idx,
                             const float* __restrict__ sc1, const float* __restrict__ sh1,
                             float* __restrict__ summed, float* __restrict__ bsum, float* __restrict__ bsq) {
  __shared__ float eL[4*16*5];
  __shared__ int gL[64];
  __shared__ float mk[64];
  __shared__ float rA[512], rB[512];
  int n0 = blockIdx.x*4;
  for (int i = threadIdx.x; i < 320; i += 512) eL[i] = edge[(size_t)n0*80 + i];
  if (threadIdx.x < 64) {
    int v = idx[n0*MM + threadIdx.x];
    mk[threadIdx.x] = v >= 0 ? 1.f : 0.f;
    gL[threadIdx.x] = v < 0 ? v + NN : v;
  }
  __syncthreads();
  int c = threadIdx.x & 127, q = threadIdx.x >> 7;
  float we[5];
  #pragma unroll
  for (int j = 0; j < 5; ++j) we[j] = Wl[(size_t)(256+j)*256 + c];
  float s = sc1[c], b = sh1[c];
  float sv = S[(size_t)(n0+q)*F + c];
  float acc = 0.f;
  for (int m = 0; m < MM; ++m) {
    int row = q*MM + m;
    float g = sv + T[(size_t)gL[row]*F + c];
    const float* e = &eL[row*5];
    #pragma unroll
    for (int j = 0; j < 5; ++j) g = fmaf(e[j], we[j], g);
    float x = fmaf(g, s, b);
    float sig = 1.f/(1.f + expf(-x));
    acc = fmaf(mk[row]*sig, sig, acc);
  }
  summed[(size_t)(n0+q)*F + c] = acc;
  rA[threadIdx.x] = acc; rB[threadIdx.x] = acc*acc;
  __syncthreads();
  if (q == 0) {
    atomicAdd(&bsum[c], rA[c]+rA[128+c]+rA[256+c]+rA[384+c]);
    atomicAdd(&bsq[c],  rB[c]+rB[128+c]+rB[256+c]+rB[384+c]);
  }
}

// node = softplus(node + bn2(summed))
__global__ void k_update(float* __restrict__ node, const float* __restrict__ summed,
                         const float* __restrict__ sc, const float* __restrict__ sh) {
  int i = blockIdx.x*256 + threadIdx.x;
  if (i >= NN*F) return;
  int c = i & 127;
  float x = node[i] + fmaf(summed[i], sc[c], sh[c]);
  node[i] = fmaxf(x, 0.f) + log1pf(expf(-fabsf(x)));
}

// fold tiled-edge / repeated-distance / constant-tp columns of pi_W1
__global__ void k_pi_const(const float* __restrict__ W1, const float* __restrict__ b1,
                           const int* __restrict__ tp,
                           float* __restrict__ w1e, float* __restrict__ w1d, float* __restrict__ b1eff) {
  int c = threadIdx.x;
  float t = read_tp(tp);
  #pragma unroll
  for (int j = 0; j < 5; ++j) w1e[j*128 + c] = W1[(128+j)*128 + c] + W1[(133+j)*128 + c];
  float d = 0.f;
  #pragma unroll
  for (int r = 138; r < 143; ++r) d += W1[r*128 + c];
  w1d[c] = d;
  float tt = 0.f;
  #pragma unroll
  for (int r = 143; r < 148; ++r) tt += W1[r*128 + c];
  b1eff[c] = b1[c] + t*tt;
}

// pack W2 (128x256) and W3 (256x128) into 3-split bf16 B-fragment layout.
// frag: 64 lanes x short8; lane&15 = out col within 16-tile, (lane>>4)*8+i = k within 32-step.
// w2p index: ((bs*4 + ks)*16 + nt)*512 + lane*8 ; w3p: ((bs*8 + ks)*8 + nt)*512 + lane*8
__global__ void k_packw(const float* __restrict__ W2, const float* __restrict__ W3,
                        short* __restrict__ w2p, short* __restrict__ w3p) {
  int tid = threadIdx.x;
  if (blockIdx.x == 0) {
    for (int it = 0; it < 8; ++it) {
      int slot = it*512 + tid;
      int ln = slot & 63, fr = slot >> 6;      // fr 0..63
      int nt = fr & 15, ks = fr >> 4;          // nt 0..15, ks 0..3
      int col = nt*16 + (ln & 15);
      int kb = ks*32 + (ln >> 4)*8;
      bf16x8 h, m, l;
      #pragma unroll
      for (int i = 0; i < 8; ++i) {
        short a, b, c;
        split3(W2[(size_t)(kb + i)*256 + col], a, b, c);
        h[i] = a; m[i] = b; l[i] = c;
      }
      *(bf16x8*)&w2p[((size_t)((0*4 + ks)*16 + nt))*512 + ln*8] = h;
      *(bf16x8*)&w2p[((size_t)((1*4 + ks)*16 + nt))*512 + ln*8] = m;
      *(bf16x8*)&w2p[((size_t)((2*4 + ks)*16 + nt))*512 + ln*8] = l;
    }
  } else {
    for (int it = 0; it < 8; ++it) {
      int slot = it*512 + tid;
      int ln = slot & 63, fr = slot >> 6;      // fr 0..63
      int nt = fr & 7, ks = fr >> 3;           // nt 0..7, ks 0..7
      int col = nt*16 + (ln & 15);
      int kb = ks*32 + (ln >> 4)*8;
      bf16x8 h, m, l;
      #pragma unroll
      for (int i = 0; i < 8; ++i) {
        short a, b, c;
        split3(W3[(size_t)(kb + i)*128 + col], a, b, c);
        h[i] = a; m[i] = b; l[i] = c;
      }
      *(bf16x8*)&w3p[((size_t)((0*8 + ks)*8 + nt))*512 + ln*8] = h;
      *(bf16x8*)&w3p[((size_t)((1*8 + ks)*8 + nt))*512 + ln*8] = m;
      *(bf16x8*)&w3p[((size_t)((2*8 + ks)*8 + nt))*512 + ln*8] = l;
    }
  }
}

// fused pi MLP via split-bf16 MFMA. 64 rows/block, 512 threads (8 waves).
// h1 splits: buf[row*392 + s*128 + k] (pad 8 -> 2-way-free bank stride)
// h2 splits: buf[row*776 + s*256 + k] (aliases h1 region across a barrier)
__global__ __launch_bounds__(512, 1) void k_pi_mfma(
    const float* __restrict__ U, const float* __restrict__ b2,
    const float* __restrict__ b3, const float* __restrict__ W4, const float* __restrict__ b4,
    const short* __restrict__ w2p, const short* __restrict__ w3p,
    const float* __restrict__ edge, const int* __restrict__ idx, const float* __restrict__ dist,
    const int* __restrict__ tp,
    const float* __restrict__ w1e, const float* __restrict__ w1d,
    float* __restrict__ lgt) {
  __shared__ __align__(16) short buf[64*776];      // 99328 B
  __shared__ float eeL[64][5];
  __shared__ float ddL[64];
  __shared__ int gxL[64], ivL[64];
  __shared__ __align__(16) float part[8][64];
  int tid = threadIdx.x;
  int rb = blockIdx.x*64;
  for (int i = tid; i < 320; i += 512) eeL[i/5][i%5] = edge[(size_t)rb*5 + i];
  if (tid < 64) {
    int v = idx[rb + tid];
    ivL[tid] = v;
    gxL[tid] = v < 0 ? v + NN : v;
    ddL[tid] = dist[rb + tid];
  }
  __syncthreads();

  // ---- stage A: h1 = relu(U[gather] + e@W1e + d*w1d), split to 3x bf16 in LDS ----
  {
    int c = tid & 127, rg = tid >> 7;
    float wd = w1d[c];
    float wE[5];
    #pragma unroll
    for (int j = 0; j < 5; ++j) wE[j] = w1e[j*128 + c];
    #pragma unroll 4
    for (int rr = 0; rr < 16; ++rr) {
      int r = rg*16 + rr;
      float v = U[(size_t)gxL[r]*F + c];
      v = fmaf(ddL[r], wd, v);
      #pragma unroll
      for (int j = 0; j < 5; ++j) v = fmaf(eeL[r][j], wE[j], v);
      v = fmaxf(v, 0.f);
      short s0, s1, s2; split3(v, s0, s1, s2);
      buf[r*392 + c] = s0; buf[r*392 + 128 + c] = s1; buf[r*392 + 256 + c] = s2;
    }
  }
  __syncthreads();

  int wv = tid >> 6, ln = tid & 63;
  int lr = ln & 15, lg2 = ln >> 4;
  f32x4v zz = {0.f, 0.f, 0.f, 0.f};

  // ---- stage B: h2 = relu(h1 @ W2 + b2); wave -> n-tiles {2wv, 2wv+1}, all 4 m-tiles ----
  f32x4v accB[4][2];
  #pragma unroll
  for (int mt = 0; mt < 4; ++mt) { accB[mt][0] = zz; accB[mt][1] = zz; }
  {
    int nt0 = wv*2, nt1 = wv*2 + 1;
    for (int ks = 0; ks < 4; ++ks) {
      #pragma unroll
      for (int bs = 0; bs < 3; ++bs) {
        bf16x8 B0 = *(const bf16x8*)&w2p[((size_t)((bs*4 + ks)*16 + nt0))*512 + ln*8];
        bf16x8 B1 = *(const bf16x8*)&w2p[((size_t)((bs*4 + ks)*16 + nt1))*512 + ln*8];
        int na = 3 - bs;   // products: (h,h)(m,h)(l,h) | (h,m)(m,m) | (h,l)
        #pragma unroll
        for (int as = 0; as < 3; ++as) {
          if (as >= na) break;
          #pragma unroll
          for (int mt = 0; mt < 4; ++mt) {
            bf16x8 a = *(const bf16x8*)&buf[(mt*16 + lr)*392 + as*128 + ks*32 + lg2*8];
            accB[mt][0] = __builtin_amdgcn_mfma_f32_16x16x32_bf16(a, B0, accB[mt][0], 0, 0, 0);
            accB[mt][1] = __builtin_amdgcn_mfma_f32_16x16x32_bf16(a, B1, accB[mt][1], 0, 0, 0);
          }
        }
      }
    }
  }
  __syncthreads();   // all waves done reading h1 region
  // write h2 splits (C/D layout: col=lane&15, row=(lane>>4)*4+reg)
  {
    #pragma unroll
    for (int ntl = 0; ntl < 2; ++ntl) {
      int col = (wv*2 + ntl)*16 + lr;
      float bb = b2[col];
      #pragma unroll
      for (int mt = 0; mt < 4; ++mt) {
        #pragma unroll
        for (int r = 0; r < 4; ++r) {
          int row = mt*16 + lg2*4 + r;
          float x = fmaxf(accB[mt][ntl][r] + bb, 0.f);
          short s0, s1, s2; split3(x, s0, s1, s2);
          buf[row*776 + col] = s0; buf[row*776 + 256 + col] = s1; buf[row*776 + 512 + col] = s2;
        }
      }
    }
  }
  __syncthreads();

  // ---- stage C: h3 = relu(h2 @ W3 + b3); wave -> n-tile wv, all 4 m-tiles ----
  f32x4v accC[4];
  #pragma unroll
  for (int mt = 0; mt < 4; ++mt) accC[mt] = zz;
  {
    for (int ks = 0; ks < 8; ++ks) {
      #pragma unroll
      for (int bs = 0; bs < 3; ++bs) {
        bf16x8 B = *(const bf16x8*)&w3p[((size_t)((bs*8 + ks)*8 + wv))*512 + ln*8];
        int na = 3 - bs;
        #pragma unroll
        for (int as = 0; as < 3; ++as) {
          if (as >= na) break;
          #pragma unroll
          for (int mt = 0; mt < 4; ++mt) {
            bf16x8 a = *(const bf16x8*)&buf[(mt*16 + lr)*776 + as*256 + ks*32 + lg2*8];
            accC[mt] = __builtin_amdgcn_mfma_f32_16x16x32_bf16(a, B, accC[mt], 0, 0, 0);
          }
        }
      }
    }
  }

  // ---- stage D: logit = relu(h3)@W4 (+b4), reduce over cols ----
  {
    float w4c = W4[wv*16 + lr];
    float b3c = b3[wv*16 + lr];
    #pragma unroll
    for (int mt = 0; mt < 4; ++mt) {
      float p0 = fmaxf(accC[mt][0] + b3c, 0.f) * w4c;
      float p1 = fmaxf(accC[mt][1] + b3c, 0.f) * w4c;
      float p2 = fmaxf(accC[mt][2] + b3c, 0.f) * w4c;
      float p3 = fmaxf(accC[mt][3] + b3c, 0.f) * w4c;
      #pragma unroll
      for (int off = 1; off < 16; off <<= 1) {
        p0 += __shfl_xor(p0, off, 16);
        p1 += __shfl_xor(p1, off, 16);
        p2 += __shfl_xor(p2, off, 16);
        p3 += __shfl_xor(p3, off, 16);
      }
      if (lr == 0) {
        f32x4v v = {p0, p1, p2, p3};
        *(f32x4v*)&part[wv][mt*16 + lg2*4] = v;
      }
    }
  }
  __syncthreads();
  if (tid < 64) {
    float s = 0.f;
    #pragma unroll
    for (int w = 0; w < 8; ++w) s += part[w][tid];
    float tpf = read_tp(tp);
    float lgv = s + b4[0];
    float am = (ivL[tid] >= 0 && eeL[tid][4] <= tpf) ? 0.f : 1.f;
    lgt[rb + tid] = lgv - 1e8f*am;
  }
}

__global__ void k_rmax(const float* __restrict__ lg, float* __restrict__ red) {
  float m = -1e30f;
  for (int i = blockIdx.x*256 + threadIdx.x; i < NMROWS; i += 512*256)
    m = fmaxf(m, lg[i]);
  __shared__ float r[256];
  r[threadIdx.x] = m;
  __syncthreads();
  for (int s = 128; s > 0; s >>= 1) {
    if (threadIdx.x < s) r[threadIdx.x] = fmaxf(r[threadIdx.x], r[threadIdx.x + s]);
    __syncthreads();
  }
  if (threadIdx.x == 0) red[blockIdx.x] = r[0];
}

__global__ void k_fmax(const float* __restrict__ red, float* __restrict__ scal) {
  __shared__ float r[512];
  r[threadIdx.x] = red[threadIdx.x];
  __syncthreads();
  for (int s = 256; s > 0; s >>= 1) {
    if (threadIdx.x < s) r[threadIdx.x] = fmaxf(r[threadIdx.x], r[threadIdx.x + s]);
    __syncthreads();
  }
  if (threadIdx.x == 0) scal[0] = r[0];
}

__global__ void k_rsum(const float* __restrict__ lg, const float* __restrict__ scal,
                       float* __restrict__ red) {
  float gm = scal[0];
  float s = 0.f;
  for (int i = blockIdx.x*256 + threadIdx.x; i < NMROWS; i += 512*256)
    s += expf(lg[i] - gm);
  __shared__ float r[256];
  r[threadIdx.x] = s;
  __syncthreads();
  for (int t = 128; t > 0; t >>= 1) {
    if (threadIdx.x < t) r[threadIdx.x] += r[threadIdx.x + t];
    __syncthreads();
  }
  if (threadIdx.x == 0) red[blockIdx.x] = r[0];
}

__global__ void k_fsum(const float* __restrict__ red, float* __restrict__ scal) {
  __shared__ float r[512];
  r[threadIdx.x] = red[threadIdx.x];
  __syncthreads();
  for (int s = 256; s > 0; s >>= 1) {
    if (threadIdx.x < s) r[threadIdx.x] += r[threadIdx.x + s];
    __syncthreads();
  }
  if (threadIdx.x == 0) { scal[1] = r[0]; scal[2] = 1.f/r[0]; }
}

__global__ void k_out(const float* __restrict__ lg, const float* __restrict__ scal,
                      float* __restrict__ out) {
  int i = blockIdx.x*256 + threadIdx.x;
  if (i >= NMROWS) return;
  out[i] = expf(lg[i] - scal[0]) * scal[2];
}

extern "C" void kernel_launch(void* const* d_in, const int* in_sizes, int n_in,
                              void* d_out, int out_size, void* d_ws, size_t ws_size,
                              hipStream_t stream) {
  (void)in_sizes; (void)n_in; (void)out_size;
  const float* node_fea = (const float*)d_in[0];
  const float* edge_fea = (const float*)d_in[1];
  const int*   eidx     = (const int*)d_in[2];
  const float* dist     = (const float*)d_in[3];
  const int*   tp       = (const int*)d_in[4];
  const float* emb_W    = (const float*)d_in[5];
  const float* emb_b    = (const float*)d_in[6];
  const float* cW       = (const float*)d_in[7];
  const float* cb       = (const float*)d_in[8];
  const float* bn1g     = (const float*)d_in[9];
  const float* bn1b     = (const float*)d_in[10];
  const float* bn2g     = (const float*)d_in[11];
  const float* bn2b     = (const float*)d_in[12];
  const float* pW1      = (const float*)d_in[13];
  const float* pb1      = (const float*)d_in[14];
  const float* pW2      = (const float*)d_in[15];
  const float* pb2      = (const float*)d_in[16];
  const float* pW3      = (const float*)d_in[17];
  const float* pb3      = (const float*)d_in[18];
  const float* pW4      = (const float*)d_in[19];
  const float* pb4      = (const float*)d_in[20];
  float* out = (float*)d_out;
  float* ws  = (float*)d_ws;

  if (ws_size < (size_t)(WS_STATS + ST_END)*sizeof(float)) return;

  float* stats = ws + WS_STATS;
  hipMemsetAsync(stats, 0, 1536*sizeof(float), stream);

  k_embed<<<15000, 256, 0, stream>>>(node_fea, emb_W, emb_b, ws + WS_NODE);

  for (int l = 0; l < 3; ++l) {
    const float* Wl = cW + (size_t)l*261*256;
    k_st<<<3750, 256, 0, stream>>>(ws + WS_NODE, Wl, cb + l*256, ws + WS_S, ws + WS_T);
    k_conv_stats<<<1875, 256, 0, stream>>>(ws + WS_S, ws + WS_T, Wl, edge_fea, eidx,
                                           stats + ST_BN1SUM + l*128, stats + ST_BN1SQ + l*128);
    k_bn_fin<<<1, 128, 0, stream>>>(stats + ST_BN1SUM + l*128, stats + ST_BN1SQ + l*128,
                                    bn1g + l*256, bn1b + l*256,
                                    stats + ST_SC1, stats + ST_SH1, 1.f/NMROWS);
    k_conv_pass2<<<7500, 512, 0, stream>>>(ws + WS_S, ws + WS_T, Wl, edge_fea, eidx,
                                           stats + ST_SC1, stats + ST_SH1,
                                           ws + WS_SUM, stats + ST_BN2SUM + l*128, stats + ST_BN2SQ + l*128);
    k_bn_fin<<<1, 128, 0, stream>>>(stats + ST_BN2SUM + l*128, stats + ST_BN2SQ + l*128,
                                    bn2g + l*128, bn2b + l*128,
                                    stats + ST_SC2, stats + ST_SH2, 1.f/NN);
    k_update<<<15000, 256, 0, stream>>>(ws + WS_NODE, ws + WS_SUM, stats + ST_SC2, stats + ST_SH2);
  }

  // pack split-bf16 weights into WS_T region (T is dead after the conv loop)
  short* w2p = (short*)(ws + WS_T);             // 196608 shorts
  short* w3p = (short*)(ws + WS_T + 98304);     // 196608 shorts
  k_packw<<<2, 512, 0, stream>>>(pW2, pW3, w2p, w3p);

  k_pi_const<<<1, 128, 0, stream>>>(pW1, pb1, tp, stats + ST_W1E, stats + ST_W1D, stats + ST_B1EFF);
  k_u<<<3750, 256, 0, stream>>>(ws + WS_NODE, pW1, stats + ST_B1EFF, ws + WS_S);
  k_pi_mfma<<<7500, 512, 0, stream>>>(ws + WS_S, pb2, pb3, pW4, pb4, w2p, w3p,
                                      edge_fea, eidx, dist, tp,
                                      stats + ST_W1E, stats + ST_W1D, ws + WS_LOGIT);

  k_rmax<<<512, 256, 0, stream>>>(ws + WS_LOGIT, ws + WS_RED);
  k_fmax<<<1, 512, 0, stream>>>(ws + WS_RED, ws + WS_SCAL);
  k_rsum<<<512, 256, 0, stream>>>(ws + WS_LOGIT, ws + WS_SCAL, ws + WS_RED);
  k_fsum<<<1, 512, 0, stream>>>(ws + WS_RED, ws + WS_SCAL);
  k_out<<<1875, 256, 0, stream>>>(ws + WS_LOGIT, ws + WS_SCAL, out);
}